// Round 3
// baseline (68.356 us; speedup 1.0000x reference)
//
#include <hip/hip_runtime.h>
#include <stdint.h>

#define LSEQ 1024
#define EDIM 32
#define NDIM 64

typedef __attribute__((ext_vector_type(8))) short short8;
typedef __attribute__((ext_vector_type(4))) float f32x4;

static __device__ __forceinline__ unsigned short f2bf(float f) {
    unsigned int u = __float_as_uint(f);
    u += 0x7FFFu + ((u >> 16) & 1u);
    return (unsigned short)(u >> 16);
}

// Kernel A: niB = node@Wi + b_pair, njB = node@Wj (f32); wpT = (Wp + I)^T in bf16
__global__ __launch_bounds__(256) void evo_pre(
    const float* __restrict__ node,   // [1024][64]
    const float* __restrict__ Wpair,  // [160][32]
    const float* __restrict__ bpair,  // [32]
    float* __restrict__ niB,          // [1024][32]
    float* __restrict__ njB,          // [1024][32]
    unsigned short* __restrict__ wpT) // [32][32] bf16, row f, col e
{
    int g = blockIdx.x * 256 + threadIdx.x;
    if (g < LSEQ * EDIM) {
        int i = g >> 5, f = g & 31;
        float acci = bpair[f];
        float accj = 0.0f;
        const float* nrow = node + i * NDIM;
        #pragma unroll
        for (int k = 0; k < NDIM; ++k) {
            float nv = nrow[k];
            acci += nv * Wpair[k * 32 + f];
            accj += nv * Wpair[(64 + k) * 32 + f];
        }
        niB[g] = acci;
        njB[g] = accj;
    } else {
        int idx = g - LSEQ * EDIM;
        if (idx < EDIM * EDIM) {
            int f = idx >> 5, e = idx & 31;
            float v = Wpair[(128 + e) * 32 + f];
            if (e == f) v += 1.0f;  // fold the +pair residual into the matmul
            wpT[f * 32 + e] = f2bf(v);
        }
    }
}

// Kernel B: one block per row i. D[f][j] = (Wp+I)^T @ pair_row^T via MFMA,
// + niB[i] + njB[j]; write pair_out (f32); accumulate j-sum; node+LN epilogue.
__global__ __launch_bounds__(256) void evo_main(
    const float* __restrict__ pair,   // [1024][1024][32]
    const float* __restrict__ node,   // [1024][64]
    const float* __restrict__ niB,    // [1024][32]
    const float* __restrict__ njB,    // [1024][32]
    const unsigned short* __restrict__ wpT,  // [32][32] bf16
    const float* __restrict__ Wnode,  // [96][64]
    const float* __restrict__ bnode,  // [64]
    const float* __restrict__ lnsc,   // [64]
    const float* __restrict__ lnof,   // [64]
    float* __restrict__ out_node,     // [1024][64]
    float* __restrict__ out_pair)     // [1024][1024][32]
{
    __shared__ float red[4][32];
    __shared__ float p2n[32];
    __shared__ float node_f[64];

    const int i    = blockIdx.x;
    const int tid  = threadIdx.x;
    const int wave = tid >> 6;
    const int lane = tid & 63;
    const int c    = lane & 15;   // MFMA col select (j-local) / A row select
    const int a    = lane >> 4;   // contiguous 8-wide K-chunk select / D row group

    if (tid < 64) node_f[tid] = node[i * 64 + tid];

    // A fragments: wpT rows f = c and c+16, K-chunk a*8..a*8+7 (held all kernel)
    const short8 af0 = *(const short8*)(wpT + c * 32 + a * 8);
    const short8 af1 = *(const short8*)(wpT + (c + 16) * 32 + a * 8);
    // niB[i][f] for f = 4a+r and 16+4a+r: constant per lane
    const f32x4 ni0 = *(const f32x4*)(niB + i * 32 + 4 * a);
    const f32x4 ni1 = *(const f32x4*)(niB + i * 32 + 4 * a + 16);

    f32x4 sum0 = {0.f, 0.f, 0.f, 0.f};
    f32x4 sum1 = {0.f, 0.f, 0.f, 0.f};
    const size_t rowbase = ((size_t)i) << 10;

    // each wave streams a contiguous 256-j span: j = wave*256 + t*16 + c
    for (int t = 0; t < 16; ++t) {
        const int jr = (wave << 8) + (t << 4) + c;
        const size_t pbase = (rowbase + jr) << 5;  // f32 element offset of pair row
        const f32x4 pa = *(const f32x4*)(pair + pbase + a * 8);
        const f32x4 pb = *(const f32x4*)(pair + pbase + a * 8 + 4);
        short8 bfrag;
        bfrag[0] = (short)f2bf(pa.x); bfrag[1] = (short)f2bf(pa.y);
        bfrag[2] = (short)f2bf(pa.z); bfrag[3] = (short)f2bf(pa.w);
        bfrag[4] = (short)f2bf(pb.x); bfrag[5] = (short)f2bf(pb.y);
        bfrag[6] = (short)f2bf(pb.z); bfrag[7] = (short)f2bf(pb.w);
        const f32x4 z = {0.f, 0.f, 0.f, 0.f};
        f32x4 acc0 = __builtin_amdgcn_mfma_f32_16x16x32_bf16(af0, bfrag, z, 0, 0, 0);
        f32x4 acc1 = __builtin_amdgcn_mfma_f32_16x16x32_bf16(af1, bfrag, z, 0, 0, 0);
        const f32x4 nj0 = *(const f32x4*)(njB + jr * 32 + 4 * a);
        const f32x4 nj1 = *(const f32x4*)(njB + jr * 32 + 4 * a + 16);
        const f32x4 o0 = acc0 + ni0 + nj0;
        const f32x4 o1 = acc1 + ni1 + nj1;
        sum0 += o0;
        sum1 += o1;
        *(f32x4*)(out_pair + pbase + 4 * a)      = o0;
        *(f32x4*)(out_pair + pbase + 4 * a + 16) = o1;
    }

    // reduce j-sums over the 16 c-lanes (low 4 lane bits)
    for (int m = 1; m < 16; m <<= 1) {
        sum0.x += __shfl_xor(sum0.x, m); sum0.y += __shfl_xor(sum0.y, m);
        sum0.z += __shfl_xor(sum0.z, m); sum0.w += __shfl_xor(sum0.w, m);
        sum1.x += __shfl_xor(sum1.x, m); sum1.y += __shfl_xor(sum1.y, m);
        sum1.z += __shfl_xor(sum1.z, m); sum1.w += __shfl_xor(sum1.w, m);
    }
    if (c == 0) {
        red[wave][4 * a + 0]      = sum0.x;
        red[wave][4 * a + 1]      = sum0.y;
        red[wave][4 * a + 2]      = sum0.z;
        red[wave][4 * a + 3]      = sum0.w;
        red[wave][16 + 4 * a + 0] = sum1.x;
        red[wave][16 + 4 * a + 1] = sum1.y;
        red[wave][16 + 4 * a + 2] = sum1.z;
        red[wave][16 + 4 * a + 3] = sum1.w;
    }
    __syncthreads();
    if (tid < 32) {
        p2n[tid] = (red[0][tid] + red[1][tid] + red[2][tid] + red[3][tid]) * (1.0f / 1024.0f);
    }
    __syncthreads();

    // epilogue: node update + LayerNorm, wave 0 only (64 lanes = 64 output cols)
    if (tid < 64) {
        float acc = node_f[tid] + bnode[tid];
        #pragma unroll 8
        for (int k = 0; k < 64; ++k)
            acc += node_f[k] * Wnode[k * 64 + tid];
        #pragma unroll 8
        for (int k = 0; k < 32; ++k)
            acc += p2n[k] * Wnode[(64 + k) * 64 + tid];
        float s = acc, s2 = acc * acc;
        for (int m = 1; m < 64; m <<= 1) {
            s  += __shfl_xor(s, m);
            s2 += __shfl_xor(s2, m);
        }
        const float mean = s * (1.0f / 64.0f);
        const float var  = s2 * (1.0f / 64.0f) - mean * mean;
        const float y = (acc - mean) * rsqrtf(var + 1e-5f) * lnsc[tid] + lnof[tid];
        out_node[i * 64 + tid] = y;
    }
}

extern "C" void kernel_launch(void* const* d_in, const int* in_sizes, int n_in,
                              void* d_out, int out_size, void* d_ws, size_t ws_size,
                              hipStream_t stream) {
    const float* node  = (const float*)d_in[0];
    const float* pair  = (const float*)d_in[1];
    const float* Wpair = (const float*)d_in[2];
    const float* bpair = (const float*)d_in[3];
    const float* Wnode = (const float*)d_in[4];
    const float* bnode = (const float*)d_in[5];
    const float* lnsc  = (const float*)d_in[6];
    const float* lnof  = (const float*)d_in[7];

    float* niB = (float*)d_ws;                        // [1024][32] f32
    float* njB = niB + LSEQ * EDIM;                   // [1024][32] f32
    unsigned short* wpT = (unsigned short*)(njB + LSEQ * EDIM);  // [32][32] bf16

    float* out_node = (float*)d_out;
    float* out_pair = out_node + LSEQ * NDIM;

    evo_pre<<<132, 256, 0, stream>>>(node, Wpair, bpair, niB, njB, wpT);
    evo_main<<<LSEQ, 256, 0, stream>>>(pair, node, niB, njB, wpT,
                                       Wnode, bnode, lnsc, lnof,
                                       out_node, out_pair);
}